// Round 14
// baseline (365.987 us; speedup 1.0000x reference)
//
#include <hip/hip_runtime.h>
#include <hip/hip_bf16.h>

// ---------------------------------------------------------------------------
// GraphSAGE 3-layer, bf16, bucket-CSR. R24 = R23 (best, 364.9us) with ONE
// change: NPART 8 -> 4 (scatter A/B probe).
//   Scatter (~53us of the 85us front) is the last unmeasured regime. 8-way
//   partitioning re-reads dst[] 8x (~28MB of front's 76MB FETCH) to buy
//   XCD-local bkt stores. NPART=4 halves read-amp + redundant blocks;
//   doubles each partition's node range (stores spread over 2 XCDs).
//   Decisive either way: read-amp-bound -> front ~78-81; store-bound ->
//   unchanged/slightly worse -> scatter at floor, composite near roofline.
// GEMM (64x128 counted-vmcnt, R23), agg, cast, prep: byte-identical.
// ---------------------------------------------------------------------------

typedef __attribute__((ext_vector_type(8))) short bf16x8;
typedef __attribute__((ext_vector_type(8))) unsigned short u16x8;
typedef __attribute__((ext_vector_type(4))) float floatx4;

constexpr int M0 = 50000, M1 = 25000, M2 = 12500;
constexpr int NODE_OFF1 = 50000, NODE_OFF2 = 75000, M_TOT = 87500;
constexpr int NSRC = 100000;
constexpr int NPART = 4;
constexpr int CAP = 64;     // bucket capacity per node

__device__ inline unsigned short f2bf(float f) {
    union { float f; unsigned int u; } v{f};
    unsigned int u = v.u;
    return (unsigned short)((u + 0x7FFFu + ((u >> 16) & 1u)) >> 16);  // RNE
}
__device__ inline float bf2f(unsigned short h) {
    union { unsigned int u; float f; } v{(unsigned int)h << 16};
    return v.f;
}

__device__ inline void gload_lds16(const void* g, void* l) {
    __builtin_amdgcn_global_load_lds(
        (const __attribute__((address_space(1))) unsigned int*)g,
        (__attribute__((address_space(3))) unsigned int*)l, 16, 0, 0);
}

// ---- fused front-end: x->bf16 cast | weight transpose | bucket scatter ----
constexpr int CAST_B = 12500;           // NSRC*256/8 / 256 (8 elems/thread)
constexpr int PREP_B = 640;

__global__ __launch_bounds__(256) void front_kernel(
    const float* __restrict__ x, unsigned short* __restrict__ xb,
    const float* __restrict__ Wn0, const float* __restrict__ Ws0,
    const float* __restrict__ Wn1, const float* __restrict__ Ws1,
    const float* __restrict__ Wn2, const float* __restrict__ Ws2,
    unsigned short* __restrict__ Wt0, unsigned short* __restrict__ Wt1,
    unsigned short* __restrict__ Wt2,
    const int* __restrict__ src0, const int* __restrict__ dst0,
    const int* __restrict__ src1, const int* __restrict__ dst1,
    const int* __restrict__ src2, const int* __restrict__ dst2,
    int* __restrict__ wptr, int* __restrict__ bkt,
    int E0, int E1, int E2)
{
    const int blk = blockIdx.x;
    if (blk < CAST_B) {
        long i = (long)blk * 256 + threadIdx.x;     // over NSRC*32 u16x8's
        float4 v0 = reinterpret_cast<const float4*>(x)[2 * i];
        float4 v1 = reinterpret_cast<const float4*>(x)[2 * i + 1];
        u16x8 o;
        o[0] = f2bf(v0.x); o[1] = f2bf(v0.y); o[2] = f2bf(v0.z); o[3] = f2bf(v0.w);
        o[4] = f2bf(v1.x); o[5] = f2bf(v1.y); o[6] = f2bf(v1.z); o[7] = f2bf(v1.w);
        reinterpret_cast<u16x8*>(xb)[i] = o;
    } else if (blk < CAST_B + PREP_B) {
        int b = blk - CAST_B;
        const float* Wn; const float* Ws; unsigned short* Wt; int N; int base;
        if (b < 256)      { Wn = Wn0; Ws = Ws0; Wt = Wt0; N = 256; base = 0; }
        else if (b < 512) { Wn = Wn1; Ws = Ws1; Wt = Wt1; N = 256; base = 256; }
        else              { Wn = Wn2; Ws = Ws2; Wt = Wt2; N = 128; base = 512; }
        int idx = (b - base) * 256 + threadIdx.x;   // over N*256, k fastest
        int n = idx >> 8, k = idx & 255;
        if (n >= N) return;
        Wt[(size_t)n * 512 + k]       = f2bf(Wn[(size_t)k * N + n]);
        Wt[(size_t)n * 512 + 256 + k] = f2bf(Ws[(size_t)k * N + n]);
    } else {
        const int b = blk - CAST_B - PREP_B;
        const int part = b & (NPART - 1);
        const int i = (b >> 2) * 256 + threadIdx.x;      // NPART=4 -> >>2
        const int lo = (int)(((long)M_TOT * part) / NPART);
        const int hi = (int)(((long)M_TOT * (part + 1)) / NPART);
        int node, j;
        const int* sp;
        if (i < E0) {
            node = dst0[i]; sp = src0; j = i;
        } else if (i < E0 + E1) {
            j = i - E0; node = NODE_OFF1 + dst1[j]; sp = src1;
        } else if (i < E0 + E1 + E2) {
            j = i - E0 - E1; node = NODE_OFF2 + dst2[j]; sp = src2;
        } else return;
        if (node >= lo && node < hi) {
            int s = sp[j];
            int p = atomicAdd(&wptr[node], 1);
            if (p < CAP) bkt[(size_t)node * CAP + p] = s;
        }
    }
}

// ---- Aggregation: 1 wave/node, 2 rows per iteration (16B/lane) ------------

__global__ __launch_bounds__(256) void aggregate_mean_bf16(
    const unsigned short* __restrict__ h, const int* __restrict__ wptr,
    const int* __restrict__ bkt, unsigned short* __restrict__ mean, int M)
{
    int gid = blockIdx.x * 256 + threadIdx.x;
    int node = gid >> 6;
    int lane = gid & 63;
    if (node >= M) return;
    int cnt = min(wptr[node], CAP);
    int sidx = bkt[(size_t)node * CAP + lane];      // whole list, 1 coalesced read
    const int half = lane >> 5;
    const int lq = lane & 31;
    const unsigned short* hb = h + lq * 8;
    float acc[8] = {};
    int pf = cnt >> 1;          // full pairs: both halves valid, no predication
    int p = 0;
    for (; p + 4 <= pf; p += 4) {
#pragma unroll
        for (int j = 0; j < 4; ++j) {
            int s = __shfl(sidx, 2 * (p + j) + half);
            u16x8 row = *(const u16x8*)(hb + (size_t)s * 256);
#pragma unroll
            for (int k = 0; k < 8; ++k) acc[k] += bf2f(row[k]);
        }
    }
    for (; p < pf; ++p) {
        int s = __shfl(sidx, 2 * p + half);
        u16x8 row = *(const u16x8*)(hb + (size_t)s * 256);
#pragma unroll
        for (int k = 0; k < 8; ++k) acc[k] += bf2f(row[k]);
    }
    if (cnt & 1) {              // odd tail: even half only
        int s = __shfl(sidx, cnt - 1);
        if (half == 0) {
            u16x8 row = *(const u16x8*)(hb + (size_t)s * 256);
#pragma unroll
            for (int k = 0; k < 8; ++k) acc[k] += bf2f(row[k]);
        }
    }
#pragma unroll
    for (int k = 0; k < 8; ++k) acc[k] += __shfl_xor(acc[k], 32);
    if (half == 0) {
        float invd = 1.0f / (float)max(cnt, 1);
        u16x8 o;
#pragma unroll
        for (int k = 0; k < 8; ++k) o[k] = f2bf(acc[k] * invd);
        *(u16x8*)(mean + (size_t)node * 256 + lq * 8) = o;
    }
}

// ---- Fused-K MFMA GEMM, 64x128 tile, counted-vmcnt 2-buffer pipeline ------

template <int RELU, int OUT_BF16>
__global__ __launch_bounds__(256) void sage_mfma(
    const unsigned short* __restrict__ A1,  // mean  [>=ceil64(M)][256]
    const unsigned short* __restrict__ A2,  // hsrc  [>=ceil64(M)][256]
    const unsigned short* __restrict__ Wt,  // [N][512]
    const float* __restrict__ bias,
    void* __restrict__ out, int M, int N)
{
    __shared__ unsigned short sA[2][64 * 64];    // 2 x 8 KB
    __shared__ unsigned short sB[2][128 * 64];   // 2 x 16 KB

    const int tid = threadIdx.x;
    const int bm = blockIdx.y * 64;
    const int bn = blockIdx.x * 128;
    const int wid = tid >> 6, lane = tid & 63;
    const int wm = (wid >> 1) * 32;
    const int wn = (wid & 1) * 64;
    const int quad = lane >> 4, l16 = lane & 15;

    const int srow = lane >> 3;
    const int swz = ((lane & 7) * 16) ^ (srow << 4);
    const int rswz = (l16 & 7) << 4;

    floatx4 acc[2][4] = {};

    auto stage = [&](int buf, int t) {
        const int k0 = t * 64;
        const unsigned short* Ab = (k0 < 256) ? A1 : A2;
        const int ak = k0 & 255;
#pragma unroll
        for (int u = 0; u < 6; ++u) {
            const int g = u * 4 + wid;            // 0..23, 8 rows each
            if (g < 8) {                          // A: 64 rows
                const int r = g * 8 + srow;
                gload_lds16((const char*)(Ab + (size_t)(bm + r) * 256 + ak) + swz,
                            (char*)(sA[buf]) + g * 1024);
            } else {                              // B: 128 rows
                const int gb = g - 8;
                const int r = gb * 8 + srow;
                gload_lds16((const char*)(Wt + (size_t)(bn + r) * 512 + k0) + swz,
                            (char*)(sB[buf]) + gb * 1024);
            }
        }
    };

    auto compute = [&](int buf) {
#pragma unroll
        for (int ks = 0; ks < 64; ks += 32) {
            bf16x8 af[2], bfr[4];
#pragma unroll
            for (int i = 0; i < 2; ++i) {
                const int row = wm + i * 16 + l16;
                af[i] = *(const bf16x8*)((const char*)(sA[buf]) + row * 128 +
                                         ((ks * 2 + quad * 16) ^ rswz));
            }
#pragma unroll
            for (int j = 0; j < 4; ++j) {
                const int row = wn + j * 16 + l16;
                bfr[j] = *(const bf16x8*)((const char*)(sB[buf]) + row * 128 +
                                          ((ks * 2 + quad * 16) ^ rswz));
            }
            __builtin_amdgcn_s_setprio(1);       // T5: favor MFMA-issuing wave
#pragma unroll
            for (int i = 0; i < 2; ++i)
#pragma unroll
                for (int j = 0; j < 4; ++j)
                    acc[i][j] = __builtin_amdgcn_mfma_f32_16x16x32_bf16(
                        af[i], bfr[j], acc[i][j], 0, 0, 0);
            __builtin_amdgcn_s_setprio(0);
        }
    };

    // prologue: two tiles in flight (12 loads outstanding per wave)
    stage(0, 0);
    stage(1, 1);

#pragma unroll
    for (int t = 0; t < 8; ++t) {
        if (t < 7) {
            asm volatile("s_waitcnt vmcnt(6)" ::: "memory");   // tile t landed
        } else {
            asm volatile("s_waitcnt vmcnt(0)" ::: "memory");
        }
        __builtin_amdgcn_s_barrier();        // all waves' t-loads landed
        __builtin_amdgcn_sched_barrier(0);   // keep ds_reads below the sync
        compute(t & 1);
        if (t < 7) {
            __builtin_amdgcn_s_barrier();    // all waves done reading buf t&1
            if (t + 2 < 8) stage(t & 1, t + 2);
        }
    }

    // epilogue: C row = quad*4 + reg, col = l16 (verified m89/m91)
#pragma unroll
    for (int j = 0; j < 4; ++j) {
        int col = bn + wn + j * 16 + l16;
        float bcol = bias[col];
#pragma unroll
        for (int i = 0; i < 2; ++i) {
#pragma unroll
            for (int r = 0; r < 4; ++r) {
                int row = bm + wm + i * 16 + quad * 4 + r;
                if (row < M) {
                    float v = acc[i][j][r] + bcol;
                    if (RELU) v = fmaxf(v, 0.0f);
                    if (OUT_BF16)
                        ((unsigned short*)out)[(size_t)row * N + col] = f2bf(v);
                    else
                        ((float*)out)[(size_t)row * N + col] = v;
                }
            }
        }
    }
}

// ---------------------------------------------------------------------------

extern "C" void kernel_launch(void* const* d_in, const int* in_sizes, int n_in,
                              void* d_out, int out_size, void* d_ws, size_t ws_size,
                              hipStream_t stream)
{
    const float* x   = (const float*)d_in[0];
    const float* Wn0 = (const float*)d_in[1];
    const float* Ws0 = (const float*)d_in[2];
    const float* b0  = (const float*)d_in[3];
    const float* Wn1 = (const float*)d_in[4];
    const float* Ws1 = (const float*)d_in[5];
    const float* b1  = (const float*)d_in[6];
    const float* Wn2 = (const float*)d_in[7];
    const float* Ws2 = (const float*)d_in[8];
    const float* b2  = (const float*)d_in[9];
    const int* src0 = (const int*)d_in[10];
    const int* dst0 = (const int*)d_in[11];
    const int* src1 = (const int*)d_in[12];
    const int* dst1 = (const int*)d_in[13];
    const int* src2 = (const int*)d_in[14];
    const int* dst2 = (const int*)d_in[15];
    const int E0 = in_sizes[10], E1 = in_sizes[12], E2 = in_sizes[14];
    const int E_tot = E0 + E1 + E2;

    // --- workspace layout ---
    unsigned short* xb   = (unsigned short*)d_ws;             // [100000][256]
    unsigned short* mean = xb   + (size_t)NSRC  * 256;        // [50048][256]
    unsigned short* h0   = mean + (size_t)50048 * 256;        // [50048][256]
    unsigned short* h1   = h0   + (size_t)50048 * 256;        // [25088][256]
    unsigned short* Wt0  = h1   + (size_t)25088 * 256;        // [256][512]
    unsigned short* Wt1  = Wt0  + 256 * 512;
    unsigned short* Wt2  = Wt1  + 256 * 512;                  // [128][512]
    int* wptr   = (int*)(Wt2 + 128 * 512);                    // [87500]
    int* bkt    = wptr + M_TOT;                               // [87500*64]
    float* outp = (float*)d_out;

    // wptr must be zero before scatter atomics (stream-ordered).
    hipMemsetAsync(wptr, 0, (size_t)M_TOT * sizeof(int), stream);

    const int sc_b = (E_tot + 255) / 256;
    front_kernel<<<dim3(CAST_B + PREP_B + NPART * sc_b), dim3(256), 0, stream>>>(
        x, xb, Wn0, Ws0, Wn1, Ws1, Wn2, Ws2, Wt0, Wt1, Wt2,
        src0, dst0, src1, dst1, src2, dst2, wptr, bkt, E0, E1, E2);

    auto run_layer = [&](const unsigned short* hin, int node_off, int M,
                         const unsigned short* Wt, const float* b,
                         void* hout, int N, bool relu, bool out_bf16) {
        aggregate_mean_bf16<<<dim3((M + 3) / 4), dim3(256), 0, stream>>>(
            hin, wptr + node_off, bkt + (size_t)node_off * CAP, mean, M);
        dim3 g(N / 128, (M + 63) / 64);
        if (out_bf16)
            sage_mfma<1, 1><<<g, dim3(256), 0, stream>>>(mean, hin, Wt, b, hout, M, N);
        else
            sage_mfma<0, 0><<<g, dim3(256), 0, stream>>>(mean, hin, Wt, b, hout, M, N);
    };

    run_layer(xb, 0,         M0, Wt0, b0, h0,   256, true,  true);
    run_layer(h0, NODE_OFF1, M1, Wt1, b1, h1,   256, true,  true);
    run_layer(h1, NODE_OFF2, M2, Wt2, b2, outp, 128, false, false);
}

// Round 15
// 359.652 us; speedup vs baseline: 1.0176x; 1.0176x over previous
//
#include <hip/hip_runtime.h>
#include <hip/hip_bf16.h>

// ---------------------------------------------------------------------------
// GraphSAGE 3-layer, bf16, bucket-CSR. R25 = R23 restored verbatim (measured
// best: 364.9us). R24's NPART 8->4 A/B REGRESSED (front 85->88.4, FETCH
// -10MB but WRITE +7MB): scatter is store/atomic-LOCALITY-bound, NPART=8 is
// the partitioning optimum. Final ledger (all measured):
//   front 85 (scatter ~53 at store-bound floor | cast ~32 | prep)
//   agg x3 70 (~493MB @ ~7TB/s = L3-BW roofline, R16 probe)
//   gemm x3 ~61 (counted-vmcnt 64x128, 3 blk/CU; 5 structures A/B'd)
//   memset+gaps+harness reset ~149 (fixed)
// GEMM: 64x128 tile, BK=64, 2-buffer counted vmcnt(6) (T4), setprio (T5),
// gload_lds16 + rule-#21 swizzle pair. Scatter: NPART=8 node-partitioned,
// src read on commit. Agg: 1 wave/node, 2 rows/iter, shfl_xor combine.
// ---------------------------------------------------------------------------

typedef __attribute__((ext_vector_type(8))) short bf16x8;
typedef __attribute__((ext_vector_type(8))) unsigned short u16x8;
typedef __attribute__((ext_vector_type(4))) float floatx4;

constexpr int M0 = 50000, M1 = 25000, M2 = 12500;
constexpr int NODE_OFF1 = 50000, NODE_OFF2 = 75000, M_TOT = 87500;
constexpr int NSRC = 100000;
constexpr int NPART = 8;
constexpr int CAP = 64;     // bucket capacity per node

__device__ inline unsigned short f2bf(float f) {
    union { float f; unsigned int u; } v{f};
    unsigned int u = v.u;
    return (unsigned short)((u + 0x7FFFu + ((u >> 16) & 1u)) >> 16);  // RNE
}
__device__ inline float bf2f(unsigned short h) {
    union { unsigned int u; float f; } v{(unsigned int)h << 16};
    return v.f;
}

__device__ inline void gload_lds16(const void* g, void* l) {
    __builtin_amdgcn_global_load_lds(
        (const __attribute__((address_space(1))) unsigned int*)g,
        (__attribute__((address_space(3))) unsigned int*)l, 16, 0, 0);
}

// ---- fused front-end: x->bf16 cast | weight transpose | bucket scatter ----
constexpr int CAST_B = 12500;           // NSRC*256/8 / 256 (8 elems/thread)
constexpr int PREP_B = 640;

__global__ __launch_bounds__(256) void front_kernel(
    const float* __restrict__ x, unsigned short* __restrict__ xb,
    const float* __restrict__ Wn0, const float* __restrict__ Ws0,
    const float* __restrict__ Wn1, const float* __restrict__ Ws1,
    const float* __restrict__ Wn2, const float* __restrict__ Ws2,
    unsigned short* __restrict__ Wt0, unsigned short* __restrict__ Wt1,
    unsigned short* __restrict__ Wt2,
    const int* __restrict__ src0, const int* __restrict__ dst0,
    const int* __restrict__ src1, const int* __restrict__ dst1,
    const int* __restrict__ src2, const int* __restrict__ dst2,
    int* __restrict__ wptr, int* __restrict__ bkt,
    int E0, int E1, int E2)
{
    const int blk = blockIdx.x;
    if (blk < CAST_B) {
        long i = (long)blk * 256 + threadIdx.x;     // over NSRC*32 u16x8's
        float4 v0 = reinterpret_cast<const float4*>(x)[2 * i];
        float4 v1 = reinterpret_cast<const float4*>(x)[2 * i + 1];
        u16x8 o;
        o[0] = f2bf(v0.x); o[1] = f2bf(v0.y); o[2] = f2bf(v0.z); o[3] = f2bf(v0.w);
        o[4] = f2bf(v1.x); o[5] = f2bf(v1.y); o[6] = f2bf(v1.z); o[7] = f2bf(v1.w);
        reinterpret_cast<u16x8*>(xb)[i] = o;
    } else if (blk < CAST_B + PREP_B) {
        int b = blk - CAST_B;
        const float* Wn; const float* Ws; unsigned short* Wt; int N; int base;
        if (b < 256)      { Wn = Wn0; Ws = Ws0; Wt = Wt0; N = 256; base = 0; }
        else if (b < 512) { Wn = Wn1; Ws = Ws1; Wt = Wt1; N = 256; base = 256; }
        else              { Wn = Wn2; Ws = Ws2; Wt = Wt2; N = 128; base = 512; }
        int idx = (b - base) * 256 + threadIdx.x;   // over N*256, k fastest
        int n = idx >> 8, k = idx & 255;
        if (n >= N) return;
        Wt[(size_t)n * 512 + k]       = f2bf(Wn[(size_t)k * N + n]);
        Wt[(size_t)n * 512 + 256 + k] = f2bf(Ws[(size_t)k * N + n]);
    } else {
        const int b = blk - CAST_B - PREP_B;
        const int part = b & (NPART - 1);
        const int i = (b >> 3) * 256 + threadIdx.x;
        const int lo = (int)(((long)M_TOT * part) / NPART);
        const int hi = (int)(((long)M_TOT * (part + 1)) / NPART);
        int node, j;
        const int* sp;
        if (i < E0) {
            node = dst0[i]; sp = src0; j = i;
        } else if (i < E0 + E1) {
            j = i - E0; node = NODE_OFF1 + dst1[j]; sp = src1;
        } else if (i < E0 + E1 + E2) {
            j = i - E0 - E1; node = NODE_OFF2 + dst2[j]; sp = src2;
        } else return;
        if (node >= lo && node < hi) {
            int s = sp[j];
            int p = atomicAdd(&wptr[node], 1);
            if (p < CAP) bkt[(size_t)node * CAP + p] = s;
        }
    }
}

// ---- Aggregation: 1 wave/node, 2 rows per iteration (16B/lane) ------------

__global__ __launch_bounds__(256) void aggregate_mean_bf16(
    const unsigned short* __restrict__ h, const int* __restrict__ wptr,
    const int* __restrict__ bkt, unsigned short* __restrict__ mean, int M)
{
    int gid = blockIdx.x * 256 + threadIdx.x;
    int node = gid >> 6;
    int lane = gid & 63;
    if (node >= M) return;
    int cnt = min(wptr[node], CAP);
    int sidx = bkt[(size_t)node * CAP + lane];      // whole list, 1 coalesced read
    const int half = lane >> 5;
    const int lq = lane & 31;
    const unsigned short* hb = h + lq * 8;
    float acc[8] = {};
    int pf = cnt >> 1;          // full pairs: both halves valid, no predication
    int p = 0;
    for (; p + 4 <= pf; p += 4) {
#pragma unroll
        for (int j = 0; j < 4; ++j) {
            int s = __shfl(sidx, 2 * (p + j) + half);
            u16x8 row = *(const u16x8*)(hb + (size_t)s * 256);
#pragma unroll
            for (int k = 0; k < 8; ++k) acc[k] += bf2f(row[k]);
        }
    }
    for (; p < pf; ++p) {
        int s = __shfl(sidx, 2 * p + half);
        u16x8 row = *(const u16x8*)(hb + (size_t)s * 256);
#pragma unroll
        for (int k = 0; k < 8; ++k) acc[k] += bf2f(row[k]);
    }
    if (cnt & 1) {              // odd tail: even half only
        int s = __shfl(sidx, cnt - 1);
        if (half == 0) {
            u16x8 row = *(const u16x8*)(hb + (size_t)s * 256);
#pragma unroll
            for (int k = 0; k < 8; ++k) acc[k] += bf2f(row[k]);
        }
    }
#pragma unroll
    for (int k = 0; k < 8; ++k) acc[k] += __shfl_xor(acc[k], 32);
    if (half == 0) {
        float invd = 1.0f / (float)max(cnt, 1);
        u16x8 o;
#pragma unroll
        for (int k = 0; k < 8; ++k) o[k] = f2bf(acc[k] * invd);
        *(u16x8*)(mean + (size_t)node * 256 + lq * 8) = o;
    }
}

// ---- Fused-K MFMA GEMM, 64x128 tile, counted-vmcnt 2-buffer pipeline ------
// C[m][n] = sum_{k<512} Acat[m][k] * Wt[n][k],  Acat = [mean | h] (K-concat).
// BM=64, BN=128, BK=64; 4 waves (2x2), each 32x64 output as acc[2][4].
// LDS: sA 2x8KB + sB 2x16KB = 48KB -> 3 blocks/CU. 6 loads/wave/step ->
// s_waitcnt vmcnt(6) (never 0 in loop). Swizzle pair (rule #21) verified.

template <int RELU, int OUT_BF16>
__global__ __launch_bounds__(256) void sage_mfma(
    const unsigned short* __restrict__ A1,  // mean  [>=ceil64(M)][256]
    const unsigned short* __restrict__ A2,  // hsrc  [>=ceil64(M)][256]
    const unsigned short* __restrict__ Wt,  // [N][512]
    const float* __restrict__ bias,
    void* __restrict__ out, int M, int N)
{
    __shared__ unsigned short sA[2][64 * 64];    // 2 x 8 KB
    __shared__ unsigned short sB[2][128 * 64];   // 2 x 16 KB

    const int tid = threadIdx.x;
    const int bm = blockIdx.y * 64;
    const int bn = blockIdx.x * 128;
    const int wid = tid >> 6, lane = tid & 63;
    const int wm = (wid >> 1) * 32;
    const int wn = (wid & 1) * 64;
    const int quad = lane >> 4, l16 = lane & 15;

    const int srow = lane >> 3;
    const int swz = ((lane & 7) * 16) ^ (srow << 4);
    const int rswz = (l16 & 7) << 4;

    floatx4 acc[2][4] = {};

    auto stage = [&](int buf, int t) {
        const int k0 = t * 64;
        const unsigned short* Ab = (k0 < 256) ? A1 : A2;
        const int ak = k0 & 255;
#pragma unroll
        for (int u = 0; u < 6; ++u) {
            const int g = u * 4 + wid;            // 0..23, 8 rows each
            if (g < 8) {                          // A: 64 rows
                const int r = g * 8 + srow;
                gload_lds16((const char*)(Ab + (size_t)(bm + r) * 256 + ak) + swz,
                            (char*)(sA[buf]) + g * 1024);
            } else {                              // B: 128 rows
                const int gb = g - 8;
                const int r = gb * 8 + srow;
                gload_lds16((const char*)(Wt + (size_t)(bn + r) * 512 + k0) + swz,
                            (char*)(sB[buf]) + gb * 1024);
            }
        }
    };

    auto compute = [&](int buf) {
#pragma unroll
        for (int ks = 0; ks < 64; ks += 32) {
            bf16x8 af[2], bfr[4];
#pragma unroll
            for (int i = 0; i < 2; ++i) {
                const int row = wm + i * 16 + l16;
                af[i] = *(const bf16x8*)((const char*)(sA[buf]) + row * 128 +
                                         ((ks * 2 + quad * 16) ^ rswz));
            }
#pragma unroll
            for (int j = 0; j < 4; ++j) {
                const int row = wn + j * 16 + l16;
                bfr[j] = *(const bf16x8*)((const char*)(sB[buf]) + row * 128 +
                                          ((ks * 2 + quad * 16) ^ rswz));
            }
            __builtin_amdgcn_s_setprio(1);       // T5: favor MFMA-issuing wave
#pragma unroll
            for (int i = 0; i < 2; ++i)
#pragma unroll
                for (int j = 0; j < 4; ++j)
                    acc[i][j] = __builtin_amdgcn_mfma_f32_16x16x32_bf16(
                        af[i], bfr[j], acc[i][j], 0, 0, 0);
            __builtin_amdgcn_s_setprio(0);
        }
    };

    // prologue: two tiles in flight (12 loads outstanding per wave)
    stage(0, 0);
    stage(1, 1);

#pragma unroll
    for (int t = 0; t < 8; ++t) {
        if (t < 7) {
            asm volatile("s_waitcnt vmcnt(6)" ::: "memory");   // tile t landed
        } else {
            asm volatile("s_waitcnt vmcnt(0)" ::: "memory");
        }
        __builtin_amdgcn_s_barrier();        // all waves' t-loads landed
        __builtin_amdgcn_sched_barrier(0);   // keep ds_reads below the sync
        compute(t & 1);
        if (t < 7) {
            __builtin_amdgcn_s_barrier();    // all waves done reading buf t&1
            if (t + 2 < 8) stage(t & 1, t + 2);
        }
    }

    // epilogue: C row = quad*4 + reg, col = l16 (verified m89/m91)
#pragma unroll
    for (int j = 0; j < 4; ++j) {
        int col = bn + wn + j * 16 + l16;
        float bcol = bias[col];
#pragma unroll
        for (int i = 0; i < 2; ++i) {
#pragma unroll
            for (int r = 0; r < 4; ++r) {
                int row = bm + wm + i * 16 + quad * 4 + r;
                if (row < M) {
                    float v = acc[i][j][r] + bcol;
                    if (RELU) v = fmaxf(v, 0.0f);
                    if (OUT_BF16)
                        ((unsigned short*)out)[(size_t)row * N + col] = f2bf(v);
                    else
                        ((float*)out)[(size_t)row * N + col] = v;
                }
            }
        }
    }
}

// ---------------------------------------------------------------------------

extern "C" void kernel_launch(void* const* d_in, const int* in_sizes, int n_in,
                              void* d_out, int out_size, void* d_ws, size_t ws_size,
                              hipStream_t stream)
{
    const float* x   = (const float*)d_in[0];
    const float* Wn0 = (const float*)d_in[1];
    const float* Ws0 = (const float*)d_in[2];
    const float* b0  = (const float*)d_in[3];
    const float* Wn1 = (const float*)d_in[4];
    const float* Ws1 = (const float*)d_in[5];
    const float* b1  = (const float*)d_in[6];
    const float* Wn2 = (const float*)d_in[7];
    const float* Ws2 = (const float*)d_in[8];
    const float* b2  = (const float*)d_in[9];
    const int* src0 = (const int*)d_in[10];
    const int* dst0 = (const int*)d_in[11];
    const int* src1 = (const int*)d_in[12];
    const int* dst1 = (const int*)d_in[13];
    const int* src2 = (const int*)d_in[14];
    const int* dst2 = (const int*)d_in[15];
    const int E0 = in_sizes[10], E1 = in_sizes[12], E2 = in_sizes[14];
    const int E_tot = E0 + E1 + E2;

    // --- workspace layout ---
    unsigned short* xb   = (unsigned short*)d_ws;             // [100000][256]
    unsigned short* mean = xb   + (size_t)NSRC  * 256;        // [50048][256]
    unsigned short* h0   = mean + (size_t)50048 * 256;        // [50048][256]
    unsigned short* h1   = h0   + (size_t)50048 * 256;        // [25088][256]
    unsigned short* Wt0  = h1   + (size_t)25088 * 256;        // [256][512]
    unsigned short* Wt1  = Wt0  + 256 * 512;
    unsigned short* Wt2  = Wt1  + 256 * 512;                  // [128][512]
    int* wptr   = (int*)(Wt2 + 128 * 512);                    // [87500]
    int* bkt    = wptr + M_TOT;                               // [87500*64]
    float* outp = (float*)d_out;

    // wptr must be zero before scatter atomics (stream-ordered).
    hipMemsetAsync(wptr, 0, (size_t)M_TOT * sizeof(int), stream);

    const int sc_b = (E_tot + 255) / 256;
    front_kernel<<<dim3(CAST_B + PREP_B + NPART * sc_b), dim3(256), 0, stream>>>(
        x, xb, Wn0, Ws0, Wn1, Ws1, Wn2, Ws2, Wt0, Wt1, Wt2,
        src0, dst0, src1, dst1, src2, dst2, wptr, bkt, E0, E1, E2);

    auto run_layer = [&](const unsigned short* hin, int node_off, int M,
                         const unsigned short* Wt, const float* b,
                         void* hout, int N, bool relu, bool out_bf16) {
        aggregate_mean_bf16<<<dim3((M + 3) / 4), dim3(256), 0, stream>>>(
            hin, wptr + node_off, bkt + (size_t)node_off * CAP, mean, M);
        dim3 g(N / 128, (M + 63) / 64);
        if (out_bf16)
            sage_mfma<1, 1><<<g, dim3(256), 0, stream>>>(mean, hin, Wt, b, hout, M, N);
        else
            sage_mfma<0, 0><<<g, dim3(256), 0, stream>>>(mean, hin, Wt, b, hout, M, N);
    };

    run_layer(xb, 0,         M0, Wt0, b0, h0,   256, true,  true);
    run_layer(h0, NODE_OFF1, M1, Wt1, b1, h1,   256, true,  true);
    run_layer(h1, NODE_OFF2, M2, Wt2, b2, outp, 128, false, false);
}